// Round 1
// baseline (24593.097 us; speedup 1.0000x reference)
//
#include <hip/hip_runtime.h>

#define L_SEQ 128
#define BATCH 512
#define DIM   512

typedef __attribute__((ext_vector_type(8))) short bf16x8;
typedef __attribute__((ext_vector_type(4))) float f32x4;
typedef unsigned short ushort_t;

#define MFMA16(a,b,c) __builtin_amdgcn_mfma_f32_16x16x32_bf16((a),(b),(c),0,0,0)

__device__ __forceinline__ ushort_t f2bf(float f) {
  union { float f; unsigned u; } v; v.f = f;
  unsigned u = v.u;
  unsigned r = (u + 0x7FFFu + ((u >> 16) & 1u)) >> 16;  // RNE
  return (ushort_t)r;
}
__device__ __forceinline__ float bf2f(ushort_t b) {
  union { unsigned u; float f; } v; v.u = ((unsigned)b) << 16;
  return v.f;
}
// byte offset into a [rows][512] bf16 image, row stride 1024B, XOR-swizzled 16B chunks
__device__ __forceinline__ int aoff(int r, int k) {
  return (r << 10) + ((((k >> 3) ^ (r & 7)) << 4) | ((k & 7) << 1));
}
__device__ __forceinline__ float tanh_f(float x) {
  x = fminf(fmaxf(x, -15.f), 15.f);
  float e = __expf(2.f * x);
  return (e - 1.f) / (e + 1.f);
}
__device__ __forceinline__ float sigm_f(float x) {
  x = fminf(fmaxf(x, -30.f), 30.f);
  return 1.f / (1.f + __expf(-x));
}

// ---- one-time weight conversion fp32 -> bf16 into ws ----
__global__ __launch_bounds__(256) void prep_w(const float* __restrict__ W1,
                                              const float* __restrict__ W2,
                                              const float* __restrict__ Whh,
                                              const float* __restrict__ Wih,
                                              ushort_t* __restrict__ wsb) {
  unsigned idx = blockIdx.x * 256u + threadIdx.x;
  if (idx < 262144u)       wsb[idx] = f2bf(W1[idx]);
  else if (idx < 524288u)  wsb[idx] = f2bf(W2[idx - 262144u]);
  else if (idx < 1310720u) wsb[idx] = f2bf(Whh[idx - 524288u]);
  else if (idx < 2097152u) wsb[idx] = f2bf(Wih[idx - 1310720u]);
}

// ---- precompute gi[i][b][0:1536] = emb[x[b,i]] @ W_ih^T + b_ih  (bf16 out) ----
__global__ __launch_bounds__(256) void gi_gemm(const float* __restrict__ emb,
                                               const int* __restrict__ x,
                                               const float* __restrict__ bih,
                                               const ushort_t* __restrict__ Wihb,
                                               ushort_t* __restrict__ gib) {
  __shared__ __align__(16) unsigned char As[64 * 1024];
  const int tid = threadIdx.x;
  const int mb = blockIdx.x;            // 0..1023  (M blocks of 64 rows, M = L*B)
  const int nb = blockIdx.y;            // 0..5     (N blocks of 256 cols of 1536)
  const int i = (mb * 64) >> 9;
  const int brow0 = (mb * 64) & 511;
  {
    int r = tid >> 2;                   // 0..63
    int xv = x[(brow0 + r) * L_SEQ + i];
    const float4* er4 = (const float4*)(emb + (size_t)xv * DIM);
#pragma unroll
    for (int cc = 0; cc < 16; ++cc) {
      int c = (tid & 3) * 16 + cc;      // chunk 0..63 (8 cols each)
      float4 fa = er4[c * 2], fb = er4[c * 2 + 1];
      union { ushort_t u[8]; bf16x8 v; } pk;
      pk.u[0] = f2bf(fa.x); pk.u[1] = f2bf(fa.y); pk.u[2] = f2bf(fa.z); pk.u[3] = f2bf(fa.w);
      pk.u[4] = f2bf(fb.x); pk.u[5] = f2bf(fb.y); pk.u[6] = f2bf(fb.z); pk.u[7] = f2bf(fb.w);
      *(bf16x8*)(As + aoff(r, c * 8)) = pk.v;
    }
  }
  __syncthreads();
  const int wave = tid >> 6, lane = tid & 63;
  const int lr = lane & 15, lg = lane >> 4;
  const int ncol0 = nb * 256 + wave * 64;
  f32x4 acc[4][4];
  f32x4 z = {0.f, 0.f, 0.f, 0.f};
#pragma unroll
  for (int mf = 0; mf < 4; ++mf)
#pragma unroll
    for (int nf = 0; nf < 4; ++nf) acc[mf][nf] = z;
  const ushort_t* wbase = Wihb + ((size_t)(ncol0 + lr) << 9) + (lg << 3);
#pragma unroll
  for (int kf = 0; kf < 16; ++kf) {
    bf16x8 a[4];
#pragma unroll
    for (int mf = 0; mf < 4; ++mf)
      a[mf] = *(const bf16x8*)(As + aoff((mf << 4) + lr, (kf << 5) + (lg << 3)));
#pragma unroll
    for (int nf = 0; nf < 4; ++nf) {
      bf16x8 b = *(const bf16x8*)(wbase + (size_t)nf * 8192 + (kf << 5));
#pragma unroll
      for (int mf = 0; mf < 4; ++mf) acc[mf][nf] = MFMA16(a[mf], b, acc[mf][nf]);
    }
  }
#pragma unroll
  for (int nf = 0; nf < 4; ++nf) {
    int col = ncol0 + (nf << 4) + lr;
    float bb = bih[col];
#pragma unroll
    for (int mf = 0; mf < 4; ++mf)
#pragma unroll
      for (int j = 0; j < 4; ++j) {
        int row = (mf << 4) + (lg << 2) + j;
        gib[(size_t)(i * BATCH + brow0 + row) * 1536 + col] = f2bf(acc[mf][nf][j] + bb);
      }
  }
}

// ---- matmul helpers: A image [16][512] bf16 in LDS, W row-major [out][512] bf16 ----
__device__ __forceinline__ void mm2f(const unsigned char* A, const ushort_t* W,
                                     int n0, int lane, f32x4 acc[2]) {
  const int lr = lane & 15, lg = lane >> 4;
  f32x4 z = {0.f, 0.f, 0.f, 0.f};
  acc[0] = z; acc[1] = z;
  const ushort_t* w0 = W + ((size_t)(n0 + lr) << 9) + (lg << 3);
#pragma unroll
  for (int kf = 0; kf < 16; ++kf) {
    bf16x8 a = *(const bf16x8*)(A + aoff(lr, (kf << 5) + (lg << 3)));
    bf16x8 p = *(const bf16x8*)(w0 + (kf << 5));
    bf16x8 q = *(const bf16x8*)(w0 + 8192 + (kf << 5));
    acc[0] = MFMA16(a, p, acc[0]);
    acc[1] = MFMA16(a, q, acc[1]);
  }
}
__device__ __forceinline__ void mm6(const unsigned char* A, const ushort_t* W,
                                    int n0, int lane, f32x4 acc[3][2]) {
  const int lr = lane & 15, lg = lane >> 4;
  f32x4 z = {0.f, 0.f, 0.f, 0.f};
#pragma unroll
  for (int g = 0; g < 3; ++g) { acc[g][0] = z; acc[g][1] = z; }
  const ushort_t* w0 = W + ((size_t)(n0 + lr) << 9) + (lg << 3);
#pragma unroll
  for (int kf = 0; kf < 16; ++kf) {
    bf16x8 a = *(const bf16x8*)(A + aoff(lr, (kf << 5) + (lg << 3)));
#pragma unroll
    for (int g = 0; g < 3; ++g) {
      bf16x8 p = *(const bf16x8*)(w0 + (size_t)g * 262144 + (kf << 5));
      bf16x8 q = *(const bf16x8*)(w0 + (size_t)g * 262144 + 8192 + (kf << 5));
      acc[g][0] = MFMA16(a, p, acc[g][0]);
      acc[g][1] = MFMA16(a, q, acc[g][1]);
    }
  }
}

// ---- persistent scan: 32 WGs x 1024 thr, WG handles 16 batch rows for all 128 steps ----
template <bool GI_PRE>
__global__ __launch_bounds__(1024) void scan_kernel(
    const float* __restrict__ t, const int* __restrict__ x,
    const float* __restrict__ emb,
    const ushort_t* __restrict__ W1b, const ushort_t* __restrict__ W2b,
    const ushort_t* __restrict__ Whhb, const ushort_t* __restrict__ Wihb,
    const float* __restrict__ b1g, const float* __restrict__ b2g,
    const float* __restrict__ bihg, const float* __restrict__ bhhg,
    const ushort_t* __restrict__ gib, float* __restrict__ out) {
  __shared__ __align__(16) unsigned char S0[16 * 1024];
  __shared__ __align__(16) unsigned char S1[16 * 1024];
  __shared__ float b1s[512], b2s[512], bhhs[1536], bihs[1536];
  __shared__ float dtrow[16], mrow[16];

  const int tid = threadIdx.x;
  const int wave = tid >> 6, lane = tid & 63;
  const int lr = lane & 15, lg = lane >> 4;
  const int n0 = wave * 32;
  const int b0 = blockIdx.x * 16;

  for (int q = tid; q < 512; q += 1024) { b1s[q] = b1g[q]; b2s[q] = b2g[q]; }
  for (int q = tid; q < 1536; q += 1024) { bhhs[q] = bhhg[q]; if (!GI_PRE) bihs[q] = bihg[q]; }
  { bf16x8 zz = {0, 0, 0, 0, 0, 0, 0, 0}; *(bf16x8*)(S0 + tid * 16) = zz; }

  float h[2][4];
#pragma unroll
  for (int nf = 0; nf < 2; ++nf)
#pragma unroll
    for (int j = 0; j < 4; ++j) h[nf][j] = 0.f;

  for (int i = 0; i < L_SEQ; ++i) {
    __syncthreads();  // protects prev-step S0 writes + dtrow/mrow reuse
    if (tid < 16) {
      int b = b0 + tid;
      int xv = x[b * L_SEQ + i];
      mrow[tid] = (xv != 0) ? 1.f : 0.f;
      float d = 1e-6f;
      if (i > 0) d = fmaxf(t[b * L_SEQ + i] - t[b * L_SEQ + i - 1], 1e-6f);
      dtrow[tid] = d;
    }
    __syncthreads();
    float dtj[4], mj[4];
#pragma unroll
    for (int j = 0; j < 4; ++j) { dtj[j] = dtrow[lg * 4 + j]; mj[j] = mrow[lg * 4 + j]; }

    if (i > 0) {
      float ksum[2][4] = {};
      for (int s = 0; s < 4; ++s) {
        f32x4 a1[2];
        mm2f(S0, W1b, n0, lane, a1);          // reads S0 (hin image)
        __syncthreads();
#pragma unroll
        for (int nf = 0; nf < 2; ++nf) {
          int col = n0 + nf * 16 + lr;
          float bb = b1s[col];
#pragma unroll
          for (int j = 0; j < 4; ++j) {
            float u = tanh_f(a1[nf][j] + bb);
            *(ushort_t*)(S1 + aoff(lg * 4 + j, col)) = f2bf(u);
          }
        }
        __syncthreads();
        f32x4 a2[2];
        mm2f(S1, W2b, n0, lane, a2);          // reads S1 (u image)
        const float wk = (s == 0 || s == 3) ? 1.f : 2.f;
        const float cs = (s < 2) ? 0.5f : 1.f;
#pragma unroll
        for (int nf = 0; nf < 2; ++nf) {
          int col = n0 + nf * 16 + lr;
          float bb = b2s[col];
#pragma unroll
          for (int j = 0; j < 4; ++j) {
            float kv = a2[nf][j] + bb;
            ksum[nf][j] += wk * kv;
            float nv;
            if (s < 3) {
              nv = h[nf][j] + cs * dtj[j] * kv;      // next RK4 eval point
            } else {
              float hev = h[nf][j] + dtj[j] * (1.f / 6.f) * ksum[nf][j];
              nv = (mj[j] > 0.5f) ? hev : h[nf][j];  // masked rows keep h
              h[nf][j] = nv;                          // h_pre for GRU
            }
            *(ushort_t*)(S0 + aoff(lg * 4 + j, col)) = f2bf(nv);
          }
        }
        __syncthreads();
      }
    }
    if (!GI_PRE) {  // stage xi = emb[x[b,i]] into S1 (bf16, swizzled)
      int r = tid >> 6;
      int c0 = tid & 63;
      int xv = x[(b0 + r) * L_SEQ + i];
      const float4* er4 = (const float4*)(emb + (size_t)xv * DIM);
      float4 fa = er4[c0 * 2], fb = er4[c0 * 2 + 1];
      union { ushort_t u[8]; bf16x8 v; } pk;
      pk.u[0] = f2bf(fa.x); pk.u[1] = f2bf(fa.y); pk.u[2] = f2bf(fa.z); pk.u[3] = f2bf(fa.w);
      pk.u[4] = f2bf(fb.x); pk.u[5] = f2bf(fb.y); pk.u[6] = f2bf(fb.z); pk.u[7] = f2bf(fb.w);
      *(bf16x8*)(S1 + aoff(r, c0 * 8)) = pk.v;
      __syncthreads();
    }
    f32x4 gh[3][2];
    mm6(S0, Whhb, n0, lane, gh);              // reads S0 (h_pre image)
    f32x4 gi[3][2];
    if (!GI_PRE) mm6(S1, Wihb, n0, lane, gi);
    __syncthreads();                           // all done reading S0 -> can rewrite
#pragma unroll
    for (int nf = 0; nf < 2; ++nf) {
      int col = n0 + nf * 16 + lr;
      float br = bhhs[col], bz = bhhs[col + 512], bn = bhhs[col + 1024];
#pragma unroll
      for (int j = 0; j < 4; ++j) {
        int row = lg * 4 + j;
        float gr_, gz_, gn_;
        if (GI_PRE) {
          const ushort_t* gp = gib + (size_t)(i * BATCH + b0 + row) * 1536 + col;
          gr_ = bf2f(gp[0]); gz_ = bf2f(gp[512]); gn_ = bf2f(gp[1024]);
        } else {
          gr_ = gi[0][nf][j] + bihs[col];
          gz_ = gi[1][nf][j] + bihs[col + 512];
          gn_ = gi[2][nf][j] + bihs[col + 1024];
        }
        float rr = sigm_f(gr_ + gh[0][nf][j] + br);
        float zz = sigm_f(gz_ + gh[1][nf][j] + bz);
        float nn = tanh_f(gn_ + rr * (gh[2][nf][j] + bn));
        float hnew = (1.f - zz) * nn + zz * h[nf][j];
        float hv = (mj[j] > 0.5f) ? hnew : h[nf][j];
        h[nf][j] = hv;
        *(ushort_t*)(S0 + aoff(row, col)) = f2bf(hv);   // next step's A image
      }
    }
  }
#pragma unroll
  for (int nf = 0; nf < 2; ++nf) {
    int col = n0 + nf * 16 + lr;
#pragma unroll
    for (int j = 0; j < 4; ++j) {
      int b = b0 + lg * 4 + j;
      out[(size_t)b * DIM + col] = h[nf][j];
    }
  }
}

extern "C" void kernel_launch(void* const* d_in, const int* in_sizes, int n_in,
                              void* d_out, int out_size, void* d_ws, size_t ws_size,
                              hipStream_t stream) {
  const float* t_   = (const float*)d_in[0];
  const float* emb  = (const float*)d_in[1];
  const float* Wih  = (const float*)d_in[2];
  const float* Whh  = (const float*)d_in[3];
  const float* bih  = (const float*)d_in[4];
  const float* bhh  = (const float*)d_in[5];
  const float* W1   = (const float*)d_in[6];
  const float* b1   = (const float*)d_in[7];
  const float* W2   = (const float*)d_in[8];
  const float* b2   = (const float*)d_in[9];
  const int*   x    = (const int*)d_in[10];
  float* out = (float*)d_out;

  ushort_t* wsb  = (ushort_t*)d_ws;
  ushort_t* W1b  = wsb;
  ushort_t* W2b  = wsb + 262144;
  ushort_t* Whhb = wsb + 524288;
  ushort_t* Wihb = wsb + 1310720;
  ushort_t* gib  = wsb + 2097152;
  const size_t need_gi = 4194304ull + 201326592ull;  // weights + bf16 gi[L][B][1536]
  const bool gi_pre = ws_size >= need_gi;

  hipLaunchKernelGGL(prep_w, dim3(8192), dim3(256), 0, stream, W1, W2, Whh, Wih, wsb);
  if (gi_pre) {
    hipLaunchKernelGGL(gi_gemm, dim3(1024, 6), dim3(256), 0, stream, emb, x, bih, Wihb, gib);
    hipLaunchKernelGGL((scan_kernel<true>), dim3(32), dim3(1024), 0, stream,
                       t_, x, emb, W1b, W2b, Whhb, Wihb, b1, b2, bih, bhh, gib, out);
  } else {
    hipLaunchKernelGGL((scan_kernel<false>), dim3(32), dim3(1024), 0, stream,
                       t_, x, emb, W1b, W2b, Whhb, Wihb, b1, b2, bih, bhh, gib, out);
  }
}

// Round 4
// 23984.808 us; speedup vs baseline: 1.0254x; 1.0254x over previous
//
#include <hip/hip_runtime.h>

#define L_SEQ 128
#define BATCH 512
#define DIM   512

typedef __attribute__((ext_vector_type(8))) short bf16x8;
typedef __attribute__((ext_vector_type(4))) float f32x4;
typedef unsigned short ushort_t;

#define MFMA16(a,b,c) __builtin_amdgcn_mfma_f32_16x16x32_bf16((a),(b),(c),0,0,0)

__device__ __forceinline__ ushort_t f2bf(float f) {
  union { float f; unsigned u; } v; v.f = f;
  unsigned u = v.u;
  unsigned r = (u + 0x7FFFu + ((u >> 16) & 1u)) >> 16;  // RNE
  return (ushort_t)r;
}
__device__ __forceinline__ float bf2f(ushort_t b) {
  union { unsigned u; float f; } v; v.u = ((unsigned)b) << 16;
  return v.f;
}
// byte offset into a [rows][512] bf16 image, row stride 1024B, XOR-swizzled 16B chunks
__device__ __forceinline__ int aoff(int r, int k) {
  return (r << 10) + ((((k >> 3) ^ (r & 7)) << 4) | ((k & 7) << 1));
}
__device__ __forceinline__ float tanh_f(float x) {
  x = fminf(fmaxf(x, -15.f), 15.f);
  float e = __expf(2.f * x);
  return (e - 1.f) / (e + 1.f);
}
__device__ __forceinline__ float sigm_f(float x) {
  x = fminf(fmaxf(x, -30.f), 30.f);
  return 1.f / (1.f + __expf(-x));
}

// ---- one-time weight conversion fp32 -> bf16 into ws ----
__global__ __launch_bounds__(256) void prep_w(const float* __restrict__ W1,
                                              const float* __restrict__ W2,
                                              const float* __restrict__ Whh,
                                              const float* __restrict__ Wih,
                                              ushort_t* __restrict__ wsb) {
  unsigned idx = blockIdx.x * 256u + threadIdx.x;
  if (idx < 262144u)       wsb[idx] = f2bf(W1[idx]);
  else if (idx < 524288u)  wsb[idx] = f2bf(W2[idx - 262144u]);
  else if (idx < 1310720u) wsb[idx] = f2bf(Whh[idx - 524288u]);
  else if (idx < 2097152u) wsb[idx] = f2bf(Wih[idx - 1310720u]);
}

// ---- precompute gi[i][b][0:1536] = emb[x[b,i]] @ W_ih^T + b_ih  (bf16 out, nt stores) ----
__global__ __launch_bounds__(256) void gi_gemm(const float* __restrict__ emb,
                                               const int* __restrict__ x,
                                               const float* __restrict__ bih,
                                               const ushort_t* __restrict__ Wihb,
                                               ushort_t* __restrict__ gib) {
  __shared__ __align__(16) unsigned char As[64 * 1024];
  const int tid = threadIdx.x;
  const int mb = blockIdx.x;            // 0..1023  (M blocks of 64 rows, M = L*B)
  const int nb = blockIdx.y;            // 0..5     (N blocks of 256 cols of 1536)
  const int i = (mb * 64) >> 9;
  const int brow0 = (mb * 64) & 511;
  {
    int r = tid >> 2;                   // 0..63
    int xv = x[(brow0 + r) * L_SEQ + i];
    const float4* er4 = (const float4*)(emb + (size_t)xv * DIM);
#pragma unroll
    for (int cc = 0; cc < 16; ++cc) {
      int c = (tid & 3) * 16 + cc;      // chunk 0..63 (8 cols each)
      float4 fa = er4[c * 2], fb = er4[c * 2 + 1];
      union { ushort_t u[8]; bf16x8 v; } pk;
      pk.u[0] = f2bf(fa.x); pk.u[1] = f2bf(fa.y); pk.u[2] = f2bf(fa.z); pk.u[3] = f2bf(fa.w);
      pk.u[4] = f2bf(fb.x); pk.u[5] = f2bf(fb.y); pk.u[6] = f2bf(fb.z); pk.u[7] = f2bf(fb.w);
      *(bf16x8*)(As + aoff(r, c * 8)) = pk.v;
    }
  }
  __syncthreads();
  const int wave = tid >> 6, lane = tid & 63;
  const int lr = lane & 15, lg = lane >> 4;
  const int ncol0 = nb * 256 + wave * 64;
  f32x4 acc[4][4];
  f32x4 z = {0.f, 0.f, 0.f, 0.f};
#pragma unroll
  for (int mf = 0; mf < 4; ++mf)
#pragma unroll
    for (int nf = 0; nf < 4; ++nf) acc[mf][nf] = z;
  const ushort_t* wbase = Wihb + ((size_t)(ncol0 + lr) << 9) + (lg << 3);
#pragma unroll
  for (int kf = 0; kf < 16; ++kf) {
    bf16x8 a[4];
#pragma unroll
    for (int mf = 0; mf < 4; ++mf)
      a[mf] = *(const bf16x8*)(As + aoff((mf << 4) + lr, (kf << 5) + (lg << 3)));
#pragma unroll
    for (int nf = 0; nf < 4; ++nf) {
      bf16x8 b = *(const bf16x8*)(wbase + (size_t)nf * 8192 + (kf << 5));
#pragma unroll
      for (int mf = 0; mf < 4; ++mf) acc[mf][nf] = MFMA16(a[mf], b, acc[mf][nf]);
    }
  }
#pragma unroll
  for (int nf = 0; nf < 4; ++nf) {
    int col = ncol0 + (nf << 4) + lr;
    float bb = bih[col];
#pragma unroll
    for (int mf = 0; mf < 4; ++mf)
#pragma unroll
      for (int j = 0; j < 4; ++j) {
        int row = (mf << 4) + (lg << 2) + j;
        __builtin_nontemporal_store(f2bf(acc[mf][nf][j] + bb),
            gib + (size_t)(i * BATCH + brow0 + row) * 1536 + col);
      }
  }
}

// ---- pipelined matmuls: A image [16][512] bf16 in LDS, W row-major [out][512] bf16 ----
// depth-4 prefetch ring; fully unrolled so ring indices are compile-time constants
__device__ __forceinline__ void mm2f(const unsigned char* A, const ushort_t* W,
                                     int n0, int lane, f32x4 acc[2]) {
  const int lr = lane & 15, lg = lane >> 4;
  f32x4 z = {0.f, 0.f, 0.f, 0.f};
  acc[0] = z; acc[1] = z;
  const ushort_t* w0 = W + ((size_t)(n0 + lr) << 9) + (lg << 3);
  bf16x8 pb[4], qb[4], ab[4];
#pragma unroll
  for (int i = 0; i < 4; ++i) {
    pb[i] = *(const bf16x8*)(w0 + (i << 5));
    qb[i] = *(const bf16x8*)(w0 + 8192 + (i << 5));
    ab[i] = *(const bf16x8*)(A + aoff(lr, (i << 5) + (lg << 3)));
  }
#pragma unroll
  for (int kf = 0; kf < 16; ++kf) {
    bf16x8 a = ab[kf & 3], p = pb[kf & 3], q = qb[kf & 3];
    if (kf < 12) {
      pb[kf & 3] = *(const bf16x8*)(w0 + ((kf + 4) << 5));
      qb[kf & 3] = *(const bf16x8*)(w0 + 8192 + ((kf + 4) << 5));
      ab[kf & 3] = *(const bf16x8*)(A + aoff(lr, ((kf + 4) << 5) + (lg << 3)));
    }
    acc[0] = MFMA16(a, p, acc[0]);
    acc[1] = MFMA16(a, q, acc[1]);
  }
}
// 6 output streams (3 gates x 2 col-fragments), depth-2 prefetch ring
__device__ __forceinline__ void mm6(const unsigned char* A, const ushort_t* W,
                                    int n0, int lane, f32x4 acc[3][2]) {
  const int lr = lane & 15, lg = lane >> 4;
  f32x4 z = {0.f, 0.f, 0.f, 0.f};
#pragma unroll
  for (int g = 0; g < 3; ++g) { acc[g][0] = z; acc[g][1] = z; }
  const ushort_t* w0 = W + ((size_t)(n0 + lr) << 9) + (lg << 3);
  bf16x8 wb[2][6], ab[2];
#pragma unroll
  for (int i = 0; i < 2; ++i) {
    ab[i] = *(const bf16x8*)(A + aoff(lr, (i << 5) + (lg << 3)));
#pragma unroll
    for (int g = 0; g < 3; ++g) {
      wb[i][2 * g]     = *(const bf16x8*)(w0 + (size_t)g * 262144 + (i << 5));
      wb[i][2 * g + 1] = *(const bf16x8*)(w0 + (size_t)g * 262144 + 8192 + (i << 5));
    }
  }
#pragma unroll
  for (int kf = 0; kf < 16; ++kf) {
    bf16x8 a = ab[kf & 1];
    bf16x8 w[6];
#pragma unroll
    for (int g = 0; g < 6; ++g) w[g] = wb[kf & 1][g];
    if (kf < 14) {
      ab[kf & 1] = *(const bf16x8*)(A + aoff(lr, ((kf + 2) << 5) + (lg << 3)));
#pragma unroll
      for (int g = 0; g < 3; ++g) {
        wb[kf & 1][2 * g]     = *(const bf16x8*)(w0 + (size_t)g * 262144 + ((kf + 2) << 5));
        wb[kf & 1][2 * g + 1] = *(const bf16x8*)(w0 + (size_t)g * 262144 + 8192 + ((kf + 2) << 5));
      }
    }
#pragma unroll
    for (int g = 0; g < 3; ++g) {
      acc[g][0] = MFMA16(a, w[2 * g], acc[g][0]);
      acc[g][1] = MFMA16(a, w[2 * g + 1], acc[g][1]);
    }
  }
}

// ---- persistent scan: 32 WGs x 1024 thr, WG handles 16 batch rows for all 128 steps ----
template <bool GI_PRE>
__global__ __launch_bounds__(1024, 4) void scan_kernel(
    const float* __restrict__ t, const int* __restrict__ x,
    const float* __restrict__ emb,
    const ushort_t* __restrict__ W1b, const ushort_t* __restrict__ W2b,
    const ushort_t* __restrict__ Whhb, const ushort_t* __restrict__ Wihb,
    const float* __restrict__ b1g, const float* __restrict__ b2g,
    const float* __restrict__ bihg, const float* __restrict__ bhhg,
    const ushort_t* __restrict__ gib, float* __restrict__ out) {
  __shared__ __align__(16) unsigned char S0[16 * 1024];
  __shared__ __align__(16) unsigned char S1[2][16 * 1024];
  __shared__ float b1s[512], b2s[512], bhhs[1536];
  __shared__ float bihs[GI_PRE ? 4 : 1536];

  const int tid = threadIdx.x;
  const int wave = tid >> 6, lane = tid & 63;
  const int lr = lane & 15, lg = lane >> 4;
  const int n0 = wave * 32;
  const int b0 = blockIdx.x * 16;

  for (int q = tid; q < 512; q += 1024) { b1s[q] = b1g[q]; b2s[q] = b2g[q]; }
  for (int q = tid; q < 1536; q += 1024) { bhhs[q] = bhhg[q]; if (!GI_PRE) bihs[q] = bihg[q]; }
  { bf16x8 zz = {0, 0, 0, 0, 0, 0, 0, 0}; *(bf16x8*)(S0 + tid * 16) = zz; }

  float h[2][4];
#pragma unroll
  for (int nf = 0; nf < 2; ++nf)
#pragma unroll
    for (int j = 0; j < 4; ++j) h[nf][j] = 0.f;

  for (int i = 0; i < L_SEQ; ++i) {
    __syncthreads();  // prev-step S0 epilogue writes visible to all
    // per-thread dt / mask for rows lg*4+j (redundant loads, L1-resident)
    float dtj[4], mj[4];
#pragma unroll
    for (int j = 0; j < 4; ++j) {
      int b = b0 + lg * 4 + j;
      mj[j] = (x[b * L_SEQ + i] != 0) ? 1.f : 0.f;
      float d = 1e-6f;
      if (i > 0) d = fmaxf(t[b * L_SEQ + i] - t[b * L_SEQ + i - 1], 1e-6f);
      dtj[j] = d;
    }

    if (i > 0) {
      float ksum[2][4] = {};
      for (int s = 0; s < 4; ++s) {
        f32x4 a1[2];
        mm2f(S0, W1b, n0, lane, a1);          // reads S0 (current eval point)
        // write u into S1[s&1] (last read 2 stages ago; safe — no sync needed first)
#pragma unroll
        for (int nf = 0; nf < 2; ++nf) {
          int col = n0 + nf * 16 + lr;
          float bb = b1s[col];
#pragma unroll
          for (int j = 0; j < 4; ++j)
            *(ushort_t*)(S1[s & 1] + aoff(lg * 4 + j, col)) = f2bf(tanh_f(a1[nf][j] + bb));
        }
        __syncthreads();                       // u visible; also all S0 reads done
        f32x4 a2[2];
        mm2f(S1[s & 1], W2b, n0, lane, a2);   // reads u image
        const float wk = (s == 0 || s == 3) ? 1.f : 2.f;
        const float cs = (s < 2) ? 0.5f : 1.f;
#pragma unroll
        for (int nf = 0; nf < 2; ++nf) {
          int col = n0 + nf * 16 + lr;
          float bb = b2s[col];
#pragma unroll
          for (int j = 0; j < 4; ++j) {
            float kv = a2[nf][j] + bb;
            ksum[nf][j] += wk * kv;
            float nv;
            if (s < 3) {
              nv = h[nf][j] + cs * dtj[j] * kv;      // next RK4 eval point
            } else {
              float hev = h[nf][j] + dtj[j] * (1.f / 6.f) * ksum[nf][j];
              nv = (mj[j] > 0.5f) ? hev : h[nf][j];  // masked rows keep h
              h[nf][j] = nv;                          // h_pre for GRU
            }
            *(ushort_t*)(S0 + aoff(lg * 4 + j, col)) = f2bf(nv);  // S0 readers done (sync above)
          }
        }
        __syncthreads();                       // next-point image visible
      }
    }
    if (!GI_PRE) {  // stage xi = emb[x[b,i]] into S1[0]
      int r = tid >> 6;
      int c0 = tid & 63;
      int xv = x[(b0 + r) * L_SEQ + i];
      const float4* er4 = (const float4*)(emb + (size_t)xv * DIM);
      float4 fa = er4[c0 * 2], fb = er4[c0 * 2 + 1];
      union { ushort_t u[8]; bf16x8 v; } pk;
      pk.u[0] = f2bf(fa.x); pk.u[1] = f2bf(fa.y); pk.u[2] = f2bf(fa.z); pk.u[3] = f2bf(fa.w);
      pk.u[4] = f2bf(fb.x); pk.u[5] = f2bf(fb.y); pk.u[6] = f2bf(fb.z); pk.u[7] = f2bf(fb.w);
      *(bf16x8*)(S1[0] + aoff(r, c0 * 8)) = pk.v;
      __syncthreads();
    }
    f32x4 gh[3][2];
    mm6(S0, Whhb, n0, lane, gh);              // reads S0 (h_pre image)
    f32x4 gi[3][2];
    if (!GI_PRE) mm6(S1[0], Wihb, n0, lane, gi);
    // gi precomputed: non-temporal loads (keep weights L2-resident), issued while regs are free
    ushort_t gv[3][2][4];
    if (GI_PRE) {
#pragma unroll
      for (int nf = 0; nf < 2; ++nf)
#pragma unroll
        for (int j = 0; j < 4; ++j) {
          const ushort_t* gp = gib + (size_t)(i * BATCH + b0 + lg * 4 + j) * 1536 + n0 + nf * 16 + lr;
          gv[0][nf][j] = __builtin_nontemporal_load(gp);
          gv[1][nf][j] = __builtin_nontemporal_load(gp + 512);
          gv[2][nf][j] = __builtin_nontemporal_load(gp + 1024);
        }
    }
    __syncthreads();                           // all reads of S0 done -> can rewrite
#pragma unroll
    for (int nf = 0; nf < 2; ++nf) {
      int col = n0 + nf * 16 + lr;
      float br = bhhs[col], bz = bhhs[col + 512], bn = bhhs[col + 1024];
#pragma unroll
      for (int j = 0; j < 4; ++j) {
        int row = lg * 4 + j;
        float gr_, gz_, gn_;
        if (GI_PRE) {
          gr_ = bf2f(gv[0][nf][j]); gz_ = bf2f(gv[1][nf][j]); gn_ = bf2f(gv[2][nf][j]);
        } else {
          gr_ = gi[0][nf][j] + bihs[col];
          gz_ = gi[1][nf][j] + bihs[col + 512];
          gn_ = gi[2][nf][j] + bihs[col + 1024];
        }
        float rr = sigm_f(gr_ + gh[0][nf][j] + br);
        float zz = sigm_f(gz_ + gh[1][nf][j] + bz);
        float nn = tanh_f(gn_ + rr * (gh[2][nf][j] + bn));
        float hnew = (1.f - zz) * nn + zz * h[nf][j];
        float hv = (mj[j] > 0.5f) ? hnew : h[nf][j];
        h[nf][j] = hv;
        *(ushort_t*)(S0 + aoff(row, col)) = f2bf(hv);   // next step's A image
      }
    }
  }
#pragma unroll
  for (int nf = 0; nf < 2; ++nf) {
    int col = n0 + nf * 16 + lr;
#pragma unroll
    for (int j = 0; j < 4; ++j) {
      int b = b0 + lg * 4 + j;
      out[(size_t)b * DIM + col] = h[nf][j];
    }
  }
}

extern "C" void kernel_launch(void* const* d_in, const int* in_sizes, int n_in,
                              void* d_out, int out_size, void* d_ws, size_t ws_size,
                              hipStream_t stream) {
  const float* t_   = (const float*)d_in[0];
  const float* emb  = (const float*)d_in[1];
  const float* Wih  = (const float*)d_in[2];
  const float* Whh  = (const float*)d_in[3];
  const float* bih  = (const float*)d_in[4];
  const float* bhh  = (const float*)d_in[5];
  const float* W1   = (const float*)d_in[6];
  const float* b1   = (const float*)d_in[7];
  const float* W2   = (const float*)d_in[8];
  const float* b2   = (const float*)d_in[9];
  const int*   x    = (const int*)d_in[10];
  float* out = (float*)d_out;

  ushort_t* wsb  = (ushort_t*)d_ws;
  ushort_t* W1b  = wsb;
  ushort_t* W2b  = wsb + 262144;
  ushort_t* Whhb = wsb + 524288;
  ushort_t* Wihb = wsb + 1310720;
  ushort_t* gib  = wsb + 2097152;
  const size_t need_gi = 4194304ull + 201326592ull;  // weights + bf16 gi[L][B][1536]
  const bool gi_pre = ws_size >= need_gi;

  hipLaunchKernelGGL(prep_w, dim3(8192), dim3(256), 0, stream, W1, W2, Whh, Wih, wsb);
  if (gi_pre) {
    hipLaunchKernelGGL(gi_gemm, dim3(1024, 6), dim3(256), 0, stream, emb, x, bih, Wihb, gib);
    hipLaunchKernelGGL((scan_kernel<true>), dim3(32), dim3(1024), 0, stream,
                       t_, x, emb, W1b, W2b, Whhb, Wihb, b1, b2, bih, bhh, gib, out);
  } else {
    hipLaunchKernelGGL((scan_kernel<false>), dim3(32), dim3(1024), 0, stream,
                       t_, x, emb, W1b, W2b, Whhb, Wihb, b1, b2, bih, bhh, gib, out);
  }
}

// Round 5
// 7696.437 us; speedup vs baseline: 3.1954x; 3.1164x over previous
//
#include <hip/hip_runtime.h>

#define L_SEQ 128
#define BATCH 512
#define DIM   512

typedef __attribute__((ext_vector_type(8))) short bf16x8;
typedef __attribute__((ext_vector_type(4))) float f32x4;
typedef unsigned short ushort_t;

#define MFMA16(a,b,c) __builtin_amdgcn_mfma_f32_16x16x32_bf16((a),(b),(c),0,0,0)

__device__ __forceinline__ ushort_t f2bf(float f) {
  union { float f; unsigned u; } v; v.f = f;
  unsigned u = v.u;
  unsigned r = (u + 0x7FFFu + ((u >> 16) & 1u)) >> 16;  // RNE
  return (ushort_t)r;
}
__device__ __forceinline__ float bf2f(ushort_t b) {
  union { unsigned u; float f; } v; v.u = ((unsigned)b) << 16;
  return v.f;
}
// byte offset into a [rows][512] bf16 image, row stride 1024B, XOR-swizzled 16B chunks
__device__ __forceinline__ int aoff(int r, int k) {
  return (r << 10) + ((((k >> 3) ^ (r & 7)) << 4) | ((k & 7) << 1));
}
__device__ __forceinline__ float tanh_f(float x) {
  x = fminf(fmaxf(x, -15.f), 15.f);
  float e = __expf(2.f * x);
  return (e - 1.f) / (e + 1.f);
}
__device__ __forceinline__ float sigm_f(float x) {
  x = fminf(fmaxf(x, -30.f), 30.f);
  return 1.f / (1.f + __expf(-x));
}

// ============================================================================
// Weight "slice image" layout (per matrix, 512x512 bf16 = 262144 ushorts):
//   elem(c /*out col*/, k) at: s*16384 + (c>>5)*1024 + ((k>>3)&3)*256 + (c&31)*8 + (k&7)
//   where s = k>>5.  => per (wave = c>>5, slice s): 1024 ushorts (2KB) CONTIGUOUS.
// Matrices (each 262144 ushorts): 0:W1 1:W2 2:Whr 3:Whz 4:Whn 5:Wir 6:Wiz 7:Win
// gib (bf16 gi[L][B][1536]) follows at ushort offset 2097152.
// ============================================================================

__global__ __launch_bounds__(256) void prep_w(const float* __restrict__ W1,
                                              const float* __restrict__ W2,
                                              const float* __restrict__ Whh,
                                              const float* __restrict__ Wih,
                                              ushort_t* __restrict__ wsb) {
  unsigned idx = blockIdx.x * 256u + threadIdx.x;   // 0 .. 2097151
  unsigned m  = idx >> 18;
  unsigned r  = idx & 262143u;
  unsigned s  = r >> 14;
  unsigned r1 = r & 16383u;
  unsigned w  = r1 >> 10;
  unsigned r2 = r1 & 1023u;
  unsigned g  = r2 >> 8;
  unsigned r3 = r2 & 255u;
  unsigned cc = r3 >> 3;
  unsigned j  = r3 & 7u;
  unsigned c  = w * 32u + cc;
  unsigned k  = s * 32u + g * 8u + j;
  float v;
  if (m == 0)      v = W1[c * 512u + k];
  else if (m == 1) v = W2[c * 512u + k];
  else if (m < 5)  v = Whh[((m - 2u) * 512u + c) * 512u + k];
  else             v = Wih[((m - 5u) * 512u + c) * 512u + k];
  wsb[idx] = f2bf(v);
}

// ---- precompute gi[i][b][0:1536] = emb[x[b,i]] @ W_ih^T + b_ih  (bf16, nt stores) ----
__global__ __launch_bounds__(256) void gi_gemm(const float* __restrict__ emb,
                                               const int* __restrict__ x,
                                               const float* __restrict__ bih,
                                               const ushort_t* __restrict__ wsb,
                                               ushort_t* __restrict__ gib) {
  __shared__ __align__(16) unsigned char As[64 * 1024];
  const int tid = threadIdx.x;
  const int mb = blockIdx.x;            // 0..1023  (M blocks of 64 rows, M = L*B)
  const int nb = blockIdx.y;            // 0..5     (N blocks of 256 cols of 1536)
  const int i = (mb * 64) >> 9;
  const int brow0 = (mb * 64) & 511;
  {
    int r = tid >> 2;                   // 0..63
    int xv = x[(brow0 + r) * L_SEQ + i];
    const float4* er4 = (const float4*)(emb + (size_t)xv * DIM);
#pragma unroll
    for (int cc = 0; cc < 16; ++cc) {
      int c = (tid & 3) * 16 + cc;      // chunk 0..63 (8 cols each)
      float4 fa = er4[c * 2], fb = er4[c * 2 + 1];
      union { ushort_t u[8]; bf16x8 v; } pk;
      pk.u[0] = f2bf(fa.x); pk.u[1] = f2bf(fa.y); pk.u[2] = f2bf(fa.z); pk.u[3] = f2bf(fa.w);
      pk.u[4] = f2bf(fb.x); pk.u[5] = f2bf(fb.y); pk.u[6] = f2bf(fb.z); pk.u[7] = f2bf(fb.w);
      *(bf16x8*)(As + aoff(r, c * 8)) = pk.v;
    }
  }
  __syncthreads();
  const int wave = tid >> 6, lane = tid & 63;
  const int lr = lane & 15, lg = lane >> 4;
  const int ncol0 = nb * 256 + wave * 64;
  const int gate = nb >> 1;
  const ushort_t* wimg = wsb + (5u + (unsigned)gate) * 262144u;
  int bofs[4];
#pragma unroll
  for (int nf = 0; nf < 4; ++nf) {
    int cg = (nb & 1) * 256 + wave * 64 + nf * 16 + lr;  // gate-local col
    bofs[nf] = (cg >> 5) * 1024 + (cg & 31) * 8 + lg * 256;
  }
  f32x4 acc[4][4];
  f32x4 z = {0.f, 0.f, 0.f, 0.f};
#pragma unroll
  for (int mf = 0; mf < 4; ++mf)
#pragma unroll
    for (int nf = 0; nf < 4; ++nf) acc[mf][nf] = z;
#pragma unroll
  for (int kf = 0; kf < 16; ++kf) {
    bf16x8 a[4];
#pragma unroll
    for (int mf = 0; mf < 4; ++mf)
      a[mf] = *(const bf16x8*)(As + aoff((mf << 4) + lr, (kf << 5) + (lg << 3)));
#pragma unroll
    for (int nf = 0; nf < 4; ++nf) {
      bf16x8 b = *(const bf16x8*)(wimg + kf * 16384 + bofs[nf]);
#pragma unroll
      for (int mf = 0; mf < 4; ++mf) acc[mf][nf] = MFMA16(a[mf], b, acc[mf][nf]);
    }
  }
#pragma unroll
  for (int nf = 0; nf < 4; ++nf) {
    int col = ncol0 + (nf << 4) + lr;
    float bb = bih[col];
#pragma unroll
    for (int mf = 0; mf < 4; ++mf)
#pragma unroll
      for (int j = 0; j < 4; ++j) {
        int row = (mf << 4) + (lg << 2) + j;
        __builtin_nontemporal_store(f2bf(acc[mf][nf][j] + bb),
            gib + (size_t)(i * BATCH + brow0 + row) * 1536 + col);
      }
  }
}

// ============================================================================
// scan kernel: 32 WGs x 1024 thr.  Per-wave private weight ring (3 x 2KB) fed
// by global_load_lds, counted vmcnt(4), barriers never drain vmcnt.
// ============================================================================

__device__ __forceinline__ void barrier_nd() {
  asm volatile("s_waitcnt lgkmcnt(0)" ::: "memory");
  __builtin_amdgcn_s_barrier();
}

__device__ __forceinline__ void dma_slice(const ushort_t* __restrict__ wsb,
                                          int ip, int ij, int wave, int lane,
                                          unsigned char* dst) {
  unsigned moff = (ip < 8) ? ((unsigned)(ip & 1) << 18) : ((unsigned)(ip - 6) << 18);
  const ushort_t* src = wsb + moff + ((unsigned)ij << 14) + ((unsigned)wave << 10) + ((unsigned)lane << 3);
  __builtin_amdgcn_global_load_lds((const __attribute__((address_space(1))) unsigned int*)src,
                                   (__attribute__((address_space(3))) unsigned int*)dst, 16, 0, 0);
  __builtin_amdgcn_global_load_lds((const __attribute__((address_space(1))) unsigned int*)(src + 512),
                                   (__attribute__((address_space(3))) unsigned int*)(dst + 1024), 16, 0, 0);
}

// One 16x512 @ 512x512 matmul phase: consume 16 slices from the ring,
// issuing the slice 3 ahead (ring depth 3) each iteration.
__device__ __forceinline__ void phase_mm(const unsigned char* __restrict__ Aimg,
                                         unsigned char* __restrict__ wbw,
                                         const ushort_t* __restrict__ wsb,
                                         int wave, int lane,
                                         int& cslot, int& ip, int& ij, f32x4 acc[2]) {
  const int lr = lane & 15, lg = lane >> 4;
  f32x4 z = {0.f, 0.f, 0.f, 0.f};
  acc[0] = z; acc[1] = z;
#pragma unroll 2
  for (int kf = 0; kf < 16; ++kf) {
    asm volatile("s_waitcnt vmcnt(4)" ::: "memory");   // slice `cslot` landed; 2 ahead in flight
    __builtin_amdgcn_sched_barrier(0);
    unsigned char* wb = wbw + cslot * 2048;
    bf16x8 a = *(const bf16x8*)(Aimg + (lr << 10) + ((((kf << 2) + lg) ^ (lr & 7)) << 4));
    bf16x8 p = *(const bf16x8*)(wb + (lg << 9) + (lr << 4));
    bf16x8 q = *(const bf16x8*)(wb + (lg << 9) + 256 + (lr << 4));
    asm volatile("s_waitcnt lgkmcnt(0)" ::: "memory"); // reads done before slot overwrite
    __builtin_amdgcn_sched_barrier(0);
    dma_slice(wsb, ip, ij, wave, lane, wb);            // issue slice cursor (=c+3) into this slot
    if (++ij == 16) { ij = 0; if (++ip == 11) ip = 0; }
    cslot = (cslot == 2) ? 0 : cslot + 1;
    acc[0] = MFMA16(a, p, acc[0]);
    acc[1] = MFMA16(a, q, acc[1]);
  }
}

__global__ __launch_bounds__(1024, 4) void scan_kernel(
    const float* __restrict__ t, const int* __restrict__ x,
    const ushort_t* __restrict__ wsb,
    const float* __restrict__ b1g, const float* __restrict__ b2g,
    const float* __restrict__ bhhg,
    const ushort_t* __restrict__ gib, float* __restrict__ out) {
  extern __shared__ unsigned char smem[];
  unsigned char* WBUF = smem;                       // 16 waves * 3 slots * 2KB = 98304
  unsigned char* S0   = smem + 98304;               // 16KB h/eval-point image
  unsigned char* S1   = smem + 114688;              // 16KB u image
  float* b1s  = (float*)(smem + 131072);            // 512 f
  float* b2s  = (float*)(smem + 133120);            // 512 f
  float* bhhs = (float*)(smem + 135168);            // 1536 f  (total 141312 B)

  const int tid = threadIdx.x;
  const int wave = tid >> 6, lane = tid & 63;
  const int lr = lane & 15, lg = lane >> 4;
  const int n0 = wave * 32;
  const int b0 = blockIdx.x * 16;
  unsigned char* wbw = WBUF + wave * 6144;

  for (int q = tid; q < 512; q += 1024) { b1s[q] = b1g[q]; b2s[q] = b2g[q]; }
  for (int q = tid; q < 1536; q += 1024) bhhs[q] = bhhg[q];
  { bf16x8 zz = {0, 0, 0, 0, 0, 0, 0, 0}; *(bf16x8*)(S0 + tid * 16) = zz; }
  __syncthreads();

  // prologue plain loads (step 0): mask + gi; dt unused at i=0
  float dtj[4], mj[4];
#pragma unroll
  for (int j = 0; j < 4; ++j) {
    int b = b0 + lg * 4 + j;
    mj[j] = (x[b * L_SEQ + 0] != 0) ? 1.f : 0.f;
    dtj[j] = 1e-6f;
  }
  ushort_t gv[3][2][4];
#pragma unroll
  for (int nf = 0; nf < 2; ++nf)
#pragma unroll
    for (int j = 0; j < 4; ++j) {
      const ushort_t* gp = gib + (size_t)(b0 + lg * 4 + j) * 1536 + n0 + nf * 16 + lr;
      gv[0][nf][j] = __builtin_nontemporal_load(gp);
      gv[1][nf][j] = __builtin_nontemporal_load(gp + 512);
      gv[2][nf][j] = __builtin_nontemporal_load(gp + 1024);
    }

  // DMA prologue: step0 stream starts at phase 8 (Whr); issue slices 0..2
  int cslot = 0, ip = 8, ij = 0;
#pragma unroll
  for (int k = 0; k < 3; ++k) { dma_slice(wsb, ip, ij, wave, lane, wbw + k * 2048); ++ij; }

  float h[2][4];
#pragma unroll
  for (int nf = 0; nf < 2; ++nf)
#pragma unroll
    for (int j = 0; j < 4; ++j) h[nf][j] = 0.f;

  for (int i = 0; i < L_SEQ; ++i) {
    barrier_nd();                                  // prev-step S0 writes visible

    if (i > 0) {
      float ksum[2][4] = {};
      for (int s = 0; s < 4; ++s) {
        f32x4 a1[2];
        phase_mm(S0, wbw, wsb, wave, lane, cslot, ip, ij, a1);   // W1 @ eval point
#pragma unroll
        for (int nf = 0; nf < 2; ++nf) {
          int col = n0 + nf * 16 + lr;
          float bb = b1s[col];
#pragma unroll
          for (int j = 0; j < 4; ++j)
            *(ushort_t*)(S1 + aoff(lg * 4 + j, col)) = f2bf(tanh_f(a1[nf][j] + bb));
        }
        barrier_nd();                              // u visible; S0 reads done
        f32x4 a2[2];
        phase_mm(S1, wbw, wsb, wave, lane, cslot, ip, ij, a2);   // W2 @ u
        const float wk = (s == 0 || s == 3) ? 1.f : 2.f;
        const float cs = (s < 2) ? 0.5f : 1.f;
#pragma unroll
        for (int nf = 0; nf < 2; ++nf) {
          int col = n0 + nf * 16 + lr;
          float bb = b2s[col];
#pragma unroll
          for (int j = 0; j < 4; ++j) {
            float kv = a2[nf][j] + bb;
            ksum[nf][j] += wk * kv;
            float nv;
            if (s < 3) {
              nv = h[nf][j] + cs * dtj[j] * kv;    // next RK4 eval point
            } else {
              float hev = h[nf][j] + dtj[j] * (1.f / 6.f) * ksum[nf][j];
              nv = (mj[j] > 0.5f) ? hev : h[nf][j];
              h[nf][j] = nv;                        // h_pre for GRU
            }
            *(ushort_t*)(S0 + aoff(lg * 4 + j, col)) = f2bf(nv);
          }
        }
        barrier_nd();                              // next eval-point image visible
      }
    }

    // GRU gate matmuls (all read S0 = h_pre image)
    f32x4 gh0[2], gh1[2], gh2[2];
    phase_mm(S0, wbw, wsb, wave, lane, cslot, ip, ij, gh0);
    phase_mm(S0, wbw, wsb, wave, lane, cslot, ip, ij, gh1);
    phase_mm(S0, wbw, wsb, wave, lane, cslot, ip, ij, gh2);
    barrier_nd();                                  // all S0 reads complete

    // latency-tolerant plain loads for next step (only drain point)
    int in_ = (i < L_SEQ - 1) ? i + 1 : i;
    float dtn[4], mn[4];
#pragma unroll
    for (int j = 0; j < 4; ++j) {
      int b = b0 + lg * 4 + j;
      mn[j] = (x[b * L_SEQ + in_] != 0) ? 1.f : 0.f;
      dtn[j] = fmaxf(t[b * L_SEQ + in_] - t[b * L_SEQ + in_ - 1], 1e-6f);
    }
    ushort_t gvn[3][2][4];
#pragma unroll
    for (int nf = 0; nf < 2; ++nf)
#pragma unroll
      for (int j = 0; j < 4; ++j) {
        const ushort_t* gp = gib + (size_t)(in_ * BATCH + b0 + lg * 4 + j) * 1536 + n0 + nf * 16 + lr;
        gvn[0][nf][j] = __builtin_nontemporal_load(gp);
        gvn[1][nf][j] = __builtin_nontemporal_load(gp + 512);
        gvn[2][nf][j] = __builtin_nontemporal_load(gp + 1024);
      }

    // GRU epilogue
#pragma unroll
    for (int nf = 0; nf < 2; ++nf) {
      int col = n0 + nf * 16 + lr;
      float br = bhhs[col], bz = bhhs[col + 512], bn = bhhs[col + 1024];
#pragma unroll
      for (int j = 0; j < 4; ++j) {
        float rr = sigm_f(bf2f(gv[0][nf][j]) + gh0[nf][j] + br);
        float zz = sigm_f(bf2f(gv[1][nf][j]) + gh1[nf][j] + bz);
        float nn = tanh_f(bf2f(gv[2][nf][j]) + rr * (gh2[nf][j] + bn));
        float hnew = (1.f - zz) * nn + zz * h[nf][j];
        float hv = (mj[j] > 0.5f) ? hnew : h[nf][j];
        h[nf][j] = hv;
        *(ushort_t*)(S0 + aoff(lg * 4 + j, col)) = f2bf(hv);   // next step's A image
      }
    }
    // rotate per-step scalars
#pragma unroll
    for (int j = 0; j < 4; ++j) { dtj[j] = dtn[j]; mj[j] = mn[j]; }
#pragma unroll
    for (int g = 0; g < 3; ++g)
#pragma unroll
      for (int nf = 0; nf < 2; ++nf)
#pragma unroll
        for (int j = 0; j < 4; ++j) gv[g][nf][j] = gvn[g][nf][j];
  }

  asm volatile("s_waitcnt vmcnt(0)" ::: "memory");  // drain trailing DMAs
#pragma unroll
  for (int nf = 0; nf < 2; ++nf) {
    int col = n0 + nf * 16 + lr;
#pragma unroll
    for (int j = 0; j < 4; ++j) {
      int b = b0 + lg * 4 + j;
      out[(size_t)b * DIM + col] = h[nf][j];
    }
  }
}

extern "C" void kernel_launch(void* const* d_in, const int* in_sizes, int n_in,
                              void* d_out, int out_size, void* d_ws, size_t ws_size,
                              hipStream_t stream) {
  const float* t_   = (const float*)d_in[0];
  const float* emb  = (const float*)d_in[1];
  const float* Wih  = (const float*)d_in[2];
  const float* Whh  = (const float*)d_in[3];
  const float* bih  = (const float*)d_in[4];
  const float* bhh  = (const float*)d_in[5];
  const float* W1   = (const float*)d_in[6];
  const float* b1   = (const float*)d_in[7];
  const float* W2   = (const float*)d_in[8];
  const float* b2   = (const float*)d_in[9];
  const int*   x    = (const int*)d_in[10];
  float* out = (float*)d_out;
  (void)b2; (void)in_sizes; (void)n_in; (void)out_size; (void)ws_size;

  ushort_t* wsb = (ushort_t*)d_ws;                 // 2097152 ushorts of weight images
  ushort_t* gib = wsb + 2097152;                   // bf16 gi[L][B][1536]

  (void)hipFuncSetAttribute((const void*)scan_kernel,
                            hipFuncAttributeMaxDynamicSharedMemorySize, 141312);

  hipLaunchKernelGGL(prep_w, dim3(8192), dim3(256), 0, stream, W1, W2, Whh, Wih, wsb);
  hipLaunchKernelGGL(gi_gemm, dim3(1024, 6), dim3(256), 0, stream, emb, x, bih, wsb, gib);
  hipLaunchKernelGGL(scan_kernel, dim3(32), dim3(1024), 141312, stream,
                     t_, x, wsb, b1, b2, bhh, gib, out);
}